// Round 3
// baseline (346.035 us; speedup 1.0000x reference)
//
#include <hip/hip_runtime.h>

// ---------------------------------------------------------------------------
// Attention: out = softmax(BETA * (X_q Wq + bq)(X_k Wk + bk)^T) (X_v Wv + bv)
// B=4, S=2048, D=1024, KEY_DIM=VALUE_DIM=1024, BETA=1/32.
// R9 = R8 with the derived-waits port:
//  - ALL waitcnt/barrier sites are bare (no "memory" clobbers). R8's clobbered
//    asm made SIInsertWaitcnts emit vmcnt(0)+lgkmcnt(0) drains at every phase
//    boundary -> drain-every-phase ≈ 1-phase (m218 V1) -> 22% MfmaUtil.
//  - LDS fragment reads via inline-asm ds_read_b128 on AS3 offsets (compiler
//    cannot see them alias the LDS-DMA queue -> no auto-waits); each phase:
//    lgkmcnt(0) + sched_barrier(0) before the MFMA cluster (rule #18).
//  - stage/read/restage slot ledger identical to R8 (hardware-verified).
// ---------------------------------------------------------------------------

typedef __bf16 bf16x8 __attribute__((ext_vector_type(8)));
typedef float f32x4 __attribute__((ext_vector_type(4)));

#define MIB ((size_t)1 << 20)

__device__ __forceinline__ unsigned short f2b(float f) {
  unsigned int u = __float_as_uint(f);
  return (unsigned short)((u + 0x7FFFu + ((u >> 16) & 1u)) >> 16);
}

__device__ __forceinline__ void async16(const void* g, void* l) {
  __builtin_amdgcn_global_load_lds(
      (const __attribute__((address_space(1))) unsigned int*)g,
      (__attribute__((address_space(3))) unsigned int*)l, 16, 0, 0);
}

// 32-bit LDS byte offset of a generic pointer known to point into LDS.
__device__ __forceinline__ unsigned ldsoff(const unsigned short* p) {
  return (unsigned)(size_t)(const __attribute__((address_space(3))) unsigned short*)p;
}

// Raw b128 LDS read, invisible to the compiler's waitcnt insertion.
__device__ __forceinline__ bf16x8 ds_read16(unsigned off) {
  bf16x8 r;
  asm volatile("ds_read_b128 %0, %1" : "=v"(r) : "v"(off));
  return r;
}

// Stage one 128x64 bf16 half-tile (16 KB) global->LDS; 512 threads x 2 chunks.
// LDS slot (r,c) receives global chunk c^(r&7): linear LDS dest (HW req) +
// inverse-swizzled source == swizzled layout (both-sides rule).
__device__ __forceinline__ void stage_half(
    const unsigned short* __restrict__ src, unsigned short* dst, int ld,
    int tid) {
#pragma unroll
  for (int i = 0; i < 2; ++i) {
    const int e = i * 512 + tid;
    const int r = e >> 3;
    const int cg = (e & 7) ^ (r & 7);
    async16(src + (size_t)r * ld + cg * 8, dst + e * 8);
  }
}

// One C-quadrant: 4 m-frags x 2 n-frags x 2 k-steps = 16 MFMA.
template <int MO, int NO>
__device__ __forceinline__ void quad16(f32x4 (&acc)[8][4],
                                       const bf16x8 (&AV)[4][2],
                                       const bf16x8 (&BV)[2][2]) {
#pragma unroll
  for (int mi = 0; mi < 4; ++mi)
#pragma unroll
    for (int ni = 0; ni < 2; ++ni)
#pragma unroll
      for (int ks = 0; ks < 2; ++ks)
        acc[MO + mi][NO + ni] = __builtin_amdgcn_mfma_f32_16x16x32_bf16(
            AV[mi][ks], BV[ni][ks], acc[MO + mi][NO + ni], 0, 0, 0);
}

// ---------------------------------------------------------------------------
// 256x256 tile, BK=64, 8 waves (2M x 4N), per-wave 128x64 output.
// LDS 128 KiB: [buf(2)][A0 A1 B0 B1] half-tiles of 128x64 bf16 (8192 ushorts).
// Phase schedule per K-tile t (buf = t&1):
//   P1: asm-read av(m0-3)+bv0(n0-1) [12]; stage B1(t+1); lgkm(8); bar;
//       lgkm(0); schedbar; Q(0,0); bar
//   P2: asm-read bv1(n2-3) [4]; stage A1(t+1); bar; lgkm(0); schedbar;
//       Q(0,2); bar
//   P3: asm-read av(m4-7) [8]; stage B0(t+2); bar; lgkm(0); schedbar;
//       Q(4,2); bar
//   P4: stage A0(t+2); bar; schedbar; Q(4,0); vmcnt(4) [tail: vmcnt(0)]; bar
// Restage safety: B*(buf) last read in P2 (retired at P2 lgkm0) -> restaged
// P3; A*(buf) last read in P3 -> restaged P4; t+1 halves go to buf^1 (idle).
// At the end-of-tile vmcnt(4): 12 loads outstanding -> retires through
// A1(t+1), leaving exactly {B0,A0}(t+2) (4 loads) in flight.
// ---------------------------------------------------------------------------
__device__ __forceinline__ void gemm256_core(
    const unsigned short* __restrict__ A, const unsigned short* __restrict__ Bt,
    int K, int ld, int m0, int n0, unsigned short* lds, f32x4 (&acc)[8][4]) {
  const int tid = threadIdx.x;
  const int lane = tid & 63;
  const int wave = tid >> 6;
  const int wmh = wave >> 2;        // which A half this wave reads (0/1)
  const int wnh = (wave & 3) >> 1;  // which B half this wave reads (0/1)
  const int wno = (wave & 1) * 64;  // n offset inside the B half
  const int fr = lane & 15;
  const int q = lane >> 4;
  const int NT = K >> 6;

  auto ah = [&](int buf, int h) { return lds + buf * 32768 + h * 8192; };
  auto bh = [&](int buf, int h) { return lds + buf * 32768 + 16384 + h * 8192; };

  const unsigned LB = ldsoff(lds);  // byte base of LDS block

  const unsigned short* gA[2] = {A + (size_t)m0 * ld,
                                 A + (size_t)(m0 + 128) * ld};
  const unsigned short* gB[2] = {Bt + (size_t)n0 * ld,
                                 Bt + (size_t)(n0 + 128) * ld};

  // Fragment reads: byte addr = base + 2*(r*64 + ((kc ^ (r&7))<<3)).
  auto rdA = [&](bf16x8(&AV)[4][2], unsigned abase, int ro) {
#pragma unroll
    for (int mi = 0; mi < 4; ++mi) {
      const int r = ro + mi * 16 + fr;
#pragma unroll
      for (int ks = 0; ks < 2; ++ks) {
        const int kc = (ks << 2) + q;
        AV[mi][ks] =
            ds_read16(abase + ((unsigned)(r * 64 + ((kc ^ (r & 7)) << 3)) << 1));
      }
    }
  };
  auto rdB = [&](bf16x8(&BV)[2][2], unsigned bbase, int ro) {
#pragma unroll
    for (int ni = 0; ni < 2; ++ni) {
      const int r = ro + ni * 16 + fr;
#pragma unroll
      for (int ks = 0; ks < 2; ++ks) {
        const int kc = (ks << 2) + q;
        BV[ni][ks] =
            ds_read16(bbase + ((unsigned)(r * 64 + ((kc ^ (r & 7)) << 3)) << 1));
      }
    }
  };

  // Prologue: kt0 {B0,A0,B1,A1}, kt1 {B0,A0}; kt1's 2 stages stay in flight.
  stage_half(gB[0], bh(0, 0), ld, tid);
  stage_half(gA[0], ah(0, 0), ld, tid);
  stage_half(gB[1], bh(0, 1), ld, tid);
  stage_half(gA[1], ah(0, 1), ld, tid);
  stage_half(gB[0] + 64, bh(1, 0), ld, tid);
  stage_half(gA[0] + 64, ah(1, 0), ld, tid);
  asm volatile("s_waitcnt vmcnt(4)");
  __builtin_amdgcn_s_barrier();

  for (int t = 0; t < NT; ++t) {
    const int buf = t & 1;
    const unsigned ab = LB + (unsigned)(buf * 65536 + wmh * 16384);
    const unsigned bb = LB + (unsigned)(buf * 65536 + 32768 + wnh * 16384);
    bf16x8 av[4][2], bv0[2][2], bv1[2][2];

    // ---- P1
    rdA(av, ab, 0);
    rdB(bv0, bb, wno);
    if (t + 1 < NT)
      stage_half(gB[1] + (size_t)(t + 1) * 64, bh((t + 1) & 1, 1), ld, tid);
    asm volatile("s_waitcnt lgkmcnt(8)");
    __builtin_amdgcn_s_barrier();
    asm volatile("s_waitcnt lgkmcnt(0)");
    __builtin_amdgcn_sched_barrier(0);
    __builtin_amdgcn_s_setprio(1);
    quad16<0, 0>(acc, av, bv0);
    __builtin_amdgcn_s_setprio(0);
    __builtin_amdgcn_s_barrier();

    // ---- P2
    rdB(bv1, bb, wno + 32);
    if (t + 1 < NT)
      stage_half(gA[1] + (size_t)(t + 1) * 64, ah((t + 1) & 1, 1), ld, tid);
    __builtin_amdgcn_s_barrier();
    asm volatile("s_waitcnt lgkmcnt(0)");
    __builtin_amdgcn_sched_barrier(0);
    __builtin_amdgcn_s_setprio(1);
    quad16<0, 2>(acc, av, bv1);
    __builtin_amdgcn_s_setprio(0);
    __builtin_amdgcn_s_barrier();

    // ---- P3
    rdA(av, ab, 64);
    if (t + 2 < NT)
      stage_half(gB[0] + (size_t)(t + 2) * 64, bh(buf, 0), ld, tid);
    __builtin_amdgcn_s_barrier();
    asm volatile("s_waitcnt lgkmcnt(0)");
    __builtin_amdgcn_sched_barrier(0);
    __builtin_amdgcn_s_setprio(1);
    quad16<4, 2>(acc, av, bv1);
    __builtin_amdgcn_s_setprio(0);
    __builtin_amdgcn_s_barrier();

    // ---- P4
    if (t + 2 < NT)
      stage_half(gA[0] + (size_t)(t + 2) * 64, ah(buf, 0), ld, tid);
    __builtin_amdgcn_s_barrier();
    __builtin_amdgcn_sched_barrier(0);
    __builtin_amdgcn_s_setprio(1);
    quad16<4, 0>(acc, av, bv0);
    __builtin_amdgcn_s_setprio(0);
    if (t + 2 < NT) {
      asm volatile("s_waitcnt vmcnt(4)");
    } else if (t + 1 < NT) {
      asm volatile("s_waitcnt vmcnt(0)");
    }
    __builtin_amdgcn_s_barrier();
  }
}

// fp32 epilogue: C/D layout col = lane&15 (+16*ni), row = (lane>>4)*4+r (+16*mi)
__device__ __forceinline__ void store_f32(float* __restrict__ C, int ldc,
                                          int m0, int n0,
                                          const f32x4 (&acc)[8][4]) {
  const int tid = threadIdx.x;
  const int lane = tid & 63;
  const int wave = tid >> 6;
  const int wm = (wave >> 2) * 128;
  const int wn = (wave & 3) * 64;
  const int fr = lane & 15;
  const int q4 = (lane >> 4) * 4;
#pragma unroll
  for (int mi = 0; mi < 8; ++mi) {
    const int rowb = m0 + wm + mi * 16 + q4;
#pragma unroll
    for (int ni = 0; ni < 4; ++ni) {
      const int col = n0 + wn + ni * 16 + fr;
#pragma unroll
      for (int r = 0; r < 4; ++r)
        C[(size_t)(rowb + r) * ldc + col] = acc[mi][ni][r];
    }
  }
}

// ---------------------------------------------------------------------------
// Merged projection GEMM, 256x256 tiles, grid (4, 32, 3): z selects {q,k,v}.
// z=0,1: bf16 row-major out [8192,1024]; z=2: vT[b][n][s] transposed out.
// ---------------------------------------------------------------------------
struct ProjArgs {
  const unsigned short* A[3];
  const unsigned short* Bt[3];
  unsigned short* C[3];
  const float* bias[3];
};

__global__ __launch_bounds__(512, 2) void proj_gemm8(ProjArgs p) {
  __shared__ __align__(16) unsigned short lds[65536];
  const int z = blockIdx.z;
  const int m0 = blockIdx.y * 256;
  const int n0 = blockIdx.x * 256;

  f32x4 acc[8][4] = {};
  gemm256_core(p.A[z], p.Bt[z], 1024, 1024, m0, n0, lds, acc);

  const int tid = threadIdx.x;
  const int lane = tid & 63;
  const int wave = tid >> 6;
  const int wm = (wave >> 2) * 128;
  const int wn = (wave & 3) * 64;
  const int fr = lane & 15;
  const int q4 = (lane >> 4) * 4;
  const float* bias = p.bias[z];

  if (z != 2) {
    unsigned short* C = p.C[z];
#pragma unroll
    for (int ni = 0; ni < 4; ++ni) {
      const int col = n0 + wn + ni * 16 + fr;
      const float bb = bias[col];
#pragma unroll
      for (int mi = 0; mi < 8; ++mi) {
        const int rowb = m0 + wm + mi * 16 + q4;
#pragma unroll
        for (int r = 0; r < 4; ++r)
          C[(size_t)(rowb + r) * 1024 + col] = f2b(acc[mi][ni][r] + bb);
      }
    }
  } else {
    // vT: per-batch [1024, 2048]; 256-row tile never crosses a batch.
    unsigned short* C = p.C[2] + (size_t)(m0 >> 11) * (2048 * 1024);
    const int rloc = (m0 & 2047) + wm;
#pragma unroll
    for (int ni = 0; ni < 4; ++ni) {
      const int col = n0 + wn + ni * 16 + fr;
      const float bb = bias[col];
#pragma unroll
      for (int mi = 0; mi < 8; ++mi) {
        const int rowb = rloc + mi * 16 + q4;
        ushort4 o =
            make_ushort4(f2b(acc[mi][ni][0] + bb), f2b(acc[mi][ni][1] + bb),
                         f2b(acc[mi][ni][2] + bb), f2b(acc[mi][ni][3] + bb));
        *(ushort4*)&C[(size_t)col * 2048 + rowb] = o;
      }
    }
  }
}

// scores[b] = q[b] @ k[b]^T : M=N=2048, K=1024, fp32 out. grid (8,8,4).
__global__ __launch_bounds__(512, 2) void score_gemm8(
    const unsigned short* __restrict__ qb, const unsigned short* __restrict__ kb,
    float* __restrict__ sc) {
  __shared__ __align__(16) unsigned short lds[65536];
  const int bz = blockIdx.z;
  const int m0 = blockIdx.y * 256;
  const int n0 = blockIdx.x * 256;
  f32x4 acc[8][4] = {};
  gemm256_core(qb + (size_t)bz * (2048 * 1024), kb + (size_t)bz * (2048 * 1024),
               1024, 1024, m0, n0, lds, acc);
  store_f32(sc + (size_t)bz * (2048 * 2048), 2048, m0, n0, acc);
}

// part[kh][b] = P[b][:, kh*1024:+1024] @ v[b][kh*1024:+1024, :]. grid (4,8,8).
__global__ __launch_bounds__(512, 2) void pv_gemm8(
    const unsigned short* __restrict__ P, const unsigned short* __restrict__ vT,
    float* __restrict__ parts) {
  __shared__ __align__(16) unsigned short lds[65536];
  const int bz = blockIdx.z >> 1;
  const int kh = blockIdx.z & 1;
  const int m0 = blockIdx.y * 256;
  const int n0 = blockIdx.x * 256;
  f32x4 acc[8][4] = {};
  gemm256_core(P + (size_t)bz * (2048 * 2048) + (size_t)kh * 1024,
               vT + (size_t)bz * (1024 * 2048) + (size_t)kh * 1024, 1024, 2048,
               m0, n0, lds, acc);
  store_f32(parts + (size_t)kh * (4 * 2048 * 1024) +
                (size_t)bz * (2048 * 1024),
            1024, m0, n0, acc);
}

// out = p0 + p1 (split-K reduce), float4.
__global__ __launch_bounds__(256) void add2(const float4* __restrict__ a,
                                            const float4* __restrict__ b,
                                            float4* __restrict__ o, int n4) {
  const int i = blockIdx.x * 256 + threadIdx.x;
  if (i >= n4) return;
  float4 x = a[i], y = b[i];
  o[i] = make_float4(x.x + y.x, x.y + y.y, x.z + y.z, x.w + y.w);
}

// ---------------------------------------------------------------------------
// Merged cast fp32 -> bf16: blockIdx.y selects tensor {q,k,v}.
// ---------------------------------------------------------------------------
__global__ __launch_bounds__(256) void cast3(
    const float4* __restrict__ a, const float4* __restrict__ b,
    const float4* __restrict__ c, ushort4* __restrict__ oa,
    ushort4* __restrict__ ob, ushort4* __restrict__ oc, int n4) {
  const int i = blockIdx.x * 256 + threadIdx.x;
  if (i >= n4) return;
  const float4* src = (blockIdx.y == 0) ? a : (blockIdx.y == 1) ? b : c;
  ushort4* dst = (blockIdx.y == 0) ? oa : (blockIdx.y == 1) ? ob : oc;
  float4 v = src[i];
  dst[i] = make_ushort4(f2b(v.x), f2b(v.y), f2b(v.z), f2b(v.w));
}

// ---------------------------------------------------------------------------
// Merged cast + transpose W [K,N] fp32 -> WT [N,K] bf16; z selects weight.
// ---------------------------------------------------------------------------
__global__ __launch_bounds__(256) void transpose3(
    const float* __restrict__ w0, const float* __restrict__ w1,
    const float* __restrict__ w2, unsigned short* __restrict__ t0,
    unsigned short* __restrict__ t1, unsigned short* __restrict__ t2) {
  __shared__ float t[32][33];
  const int K = 1024, N = 1024;
  const float* W = (blockIdx.z == 0) ? w0 : (blockIdx.z == 1) ? w1 : w2;
  unsigned short* WT = (blockIdx.z == 0) ? t0 : (blockIdx.z == 1) ? t1 : t2;
  const int n0 = blockIdx.x * 32, k0 = blockIdx.y * 32;
  const int tx = threadIdx.x, ty = threadIdx.y;  // block (32,8)
#pragma unroll
  for (int i = 0; i < 32; i += 8)
    t[ty + i][tx] = W[(size_t)(k0 + ty + i) * N + (n0 + tx)];
  __syncthreads();
#pragma unroll
  for (int i = 0; i < 32; i += 8)
    WT[(size_t)(n0 + ty + i) * K + (k0 + tx)] = f2b(t[tx][ty + i]);
}

// ---------------------------------------------------------------------------
// Row softmax: P[row,:] = softmax(BETA * S[row,:]) as bf16. One block/row.
// ---------------------------------------------------------------------------
__global__ __launch_bounds__(256) void softmax_rows(const float* __restrict__ S,
                                                    unsigned short* __restrict__ P) {
  const int cols = 2048;
  const size_t row = blockIdx.x;
  const float4* srow = (const float4*)(S + row * cols);
  const int tid = threadIdx.x;
  const int lane = tid & 63;
  const int wave = tid >> 6;

  float4 a = srow[tid];
  float4 b = srow[tid + 256];

  float mx = fmaxf(fmaxf(fmaxf(a.x, a.y), fmaxf(a.z, a.w)),
                   fmaxf(fmaxf(b.x, b.y), fmaxf(b.z, b.w)));
#pragma unroll
  for (int o = 1; o < 64; o <<= 1) mx = fmaxf(mx, __shfl_xor(mx, o));

  __shared__ float red[8];
  if (lane == 0) red[wave] = mx;
  __syncthreads();
  mx = fmaxf(fmaxf(red[0], red[1]), fmaxf(red[2], red[3]));

  const float c = 0.03125f * 1.4426950408889634f;  // BETA * log2(e)
  float4 pa, pb;
  pa.x = exp2f((a.x - mx) * c); pa.y = exp2f((a.y - mx) * c);
  pa.z = exp2f((a.z - mx) * c); pa.w = exp2f((a.w - mx) * c);
  pb.x = exp2f((b.x - mx) * c); pb.y = exp2f((b.y - mx) * c);
  pb.z = exp2f((b.z - mx) * c); pb.w = exp2f((b.w - mx) * c);

  float sum = pa.x + pa.y + pa.z + pa.w + pb.x + pb.y + pb.z + pb.w;
#pragma unroll
  for (int o = 1; o < 64; o <<= 1) sum += __shfl_xor(sum, o);
  if (lane == 0) red[4 + wave] = sum;
  __syncthreads();
  sum = red[4] + red[5] + red[6] + red[7];

  const float inv = 1.0f / sum;
  ushort4* prow = (ushort4*)(P + row * cols);
  prow[tid] = make_ushort4(f2b(pa.x * inv), f2b(pa.y * inv), f2b(pa.z * inv),
                           f2b(pa.w * inv));
  prow[tid + 256] = make_ushort4(f2b(pb.x * inv), f2b(pb.y * inv),
                                 f2b(pb.z * inv), f2b(pb.w * inv));
}

// ---------------------------------------------------------------------------
extern "C" void kernel_launch(void* const* d_in, const int* in_sizes, int n_in,
                              void* d_out, int out_size, void* d_ws, size_t ws_size,
                              hipStream_t stream) {
  const float* query = (const float*)d_in[0];
  const float* key_ = (const float*)d_in[1];
  const float* value = (const float*)d_in[2];
  const float* Wq = (const float*)d_in[3];
  const float* bq = (const float*)d_in[4];
  const float* Wk = (const float*)d_in[5];
  const float* bk = (const float*)d_in[6];
  const float* Wv = (const float*)d_in[7];
  const float* bv = (const float*)d_in[8];
  float* out = (float*)d_out;

  char* ws = (char*)d_ws;
  // Workspace layout (peak 166 MiB):
  //   [0,6)      WqT/WkT/WvT bf16 [1024,1024]
  //   [6,54)     Xq/Xk/Xv bf16 [8192,1024]   (reused for P after projections)
  //   [54,102)   q bf16 [8192,1024], k bf16 [8192,1024], vT bf16 [4][1024,2048]
  //   [102,166)  scores fp32 [4,2048,2048]   (reused for PV split-K partials)
  unsigned short* WqT = (unsigned short*)ws;
  unsigned short* WkT = WqT + (size_t)1024 * 1024;
  unsigned short* WvT = WkT + (size_t)1024 * 1024;
  unsigned short* Xq = (unsigned short*)(ws + 6 * MIB);
  unsigned short* Xk = Xq + (size_t)8192 * 1024;
  unsigned short* Xv = Xk + (size_t)8192 * 1024;
  unsigned short* qb = (unsigned short*)(ws + 54 * MIB);
  unsigned short* kb = (unsigned short*)(ws + 70 * MIB);
  unsigned short* vT = (unsigned short*)(ws + 86 * MIB);
  float* sc = (float*)(ws + 102 * MIB);
  unsigned short* P = (unsigned short*)(ws + 6 * MIB);  // reuse X region
  float* part0 = sc;                                    // reuse scores region
  float* part1 = sc + (size_t)4 * 2048 * 1024;

  const int n4 = (4 * 2048 * 1024) / 4;
  cast3<<<dim3(n4 / 256, 3), 256, 0, stream>>>(
      (const float4*)query, (const float4*)key_, (const float4*)value,
      (ushort4*)Xq, (ushort4*)Xk, (ushort4*)Xv, n4);

  transpose3<<<dim3(32, 32, 3), dim3(32, 8), 0, stream>>>(Wq, Wk, Wv, WqT, WkT,
                                                          WvT);

  // All three projections: 256x256 tiles, grid (4,32,3) = 384 blocks.
  ProjArgs pa;
  pa.A[0] = Xq;  pa.A[1] = Xk;  pa.A[2] = Xv;
  pa.Bt[0] = WqT; pa.Bt[1] = WkT; pa.Bt[2] = WvT;
  pa.C[0] = qb;  pa.C[1] = kb;  pa.C[2] = vT;
  pa.bias[0] = bq; pa.bias[1] = bk; pa.bias[2] = bv;
  proj_gemm8<<<dim3(4, 32, 3), 512, 0, stream>>>(pa);

  // scores: 256 blocks (1/CU).
  score_gemm8<<<dim3(8, 8, 4), 512, 0, stream>>>(qb, kb, sc);

  // P = softmax(BETA * scores), bf16
  softmax_rows<<<8192, 256, 0, stream>>>(sc, P);

  // PV split-K=2: 256 blocks, partials into dead scores buffer.
  pv_gemm8<<<dim3(4, 8, 8), 512, 0, stream>>>(P, vT, part0);

  // out = part0 + part1 (full 2M float4 coverage: 8192 blocks).
  add2<<<dim3(n4 / 256), 256, 0, stream>>>(
      (const float4*)part0, (const float4*)part1, (float4*)out, n4);
}

// Round 4
// 344.048 us; speedup vs baseline: 1.0058x; 1.0058x over previous
//
#include <hip/hip_runtime.h>

// ---------------------------------------------------------------------------
// Attention: out = softmax(BETA * (X_q Wq + bq)(X_k Wk + bk)^T) (X_v Wv + bv)
// B=4, S=2048, D=1024, KEY_DIM=VALUE_DIM=1024, BETA=1/32.
// R10: abandon the 1-block/CU 8-phase lockstep (R8/R9 both null at 22%
//  MfmaUtil: all-wave barriers serialize LDS service with MFMA; no co-resident
//  block to hide stalls). Return to the m97/m103-verified structure where
//  overlap comes from MULTIPLE BLOCKS PER CU (m114):
//   - 128x128 tile, BK=64, 4 waves, 32 KiB single-buffer LDS, 2 barriers/step,
//     TN=128 (R6 ran TN=64 = half the MFMA per staged byte -> 24% util).
//   - PV split-K + add2 dropped: pv grid (8,16,4)=512 blocks writes out
//     directly (saves ~290 MB of partial traffic).
//  Swizzled-LDS (conflict-free, verified 0 in R6-R9) kept unchanged.
// ---------------------------------------------------------------------------

typedef __bf16 bf16x8 __attribute__((ext_vector_type(8)));
typedef float f32x4 __attribute__((ext_vector_type(4)));

#define MIB ((size_t)1 << 20)

__device__ __forceinline__ unsigned short f2b(float f) {
  unsigned int u = __float_as_uint(f);
  return (unsigned short)((u + 0x7FFFu + ((u >> 16) & 1u)) >> 16);
}

__device__ __forceinline__ void async16(const void* g, void* l) {
  __builtin_amdgcn_global_load_lds(
      (const __attribute__((address_space(1))) unsigned int*)g,
      (__attribute__((address_space(3))) unsigned int*)l, 16, 0, 0);
}

// ---------------------------------------------------------------------------
// Shared GEMM K-loop: acc += A_tile[128xBK] * Bt_tile[TNxBK]^T, BK=64.
// A: [M,K] bf16 row-major, Bt: [N,K] bf16 row-major.
// 4 waves arranged 2x2; each wave does 64 x (TN/2) via 4 x (TN/32) frags.
// LDS layout: row-major 64 elems/row, 16B chunk column XOR-swizzled by row
// (slot (r,cc) holds global chunk (r, cc^(r&7))) -> conflict-free reads.
// ---------------------------------------------------------------------------
template <int TN>
__device__ __forceinline__ void gemm_loop(
    const unsigned short* __restrict__ A, const unsigned short* __restrict__ Bt,
    unsigned short* lds_a, unsigned short* lds_b, int K, int m0, int n0,
    f32x4 (&acc)[4][TN / 32]) {
  constexpr int NI = TN / 32;
  const int tid = threadIdx.x;
  const int lane = tid & 63;
  const int wave = tid >> 6;
  const int wm = (wave >> 1) * 64;
  const int wn = (wave & 1) * (TN / 2);
  const int fr = lane & 15;
  const int q = lane >> 4;  // quarter-wave -> k-chunk offset

  for (int kb = 0; kb < K; kb += 64) {
#pragma unroll
    for (int i = 0; i < 4; ++i) {
      const int e = i * 256 + tid;  // chunk slot, 8 bf16 per chunk
      const int r = e >> 3;
      const int cg = (e & 7) ^ (r & 7);
      async16(A + (size_t)(m0 + r) * K + kb + cg * 8, &lds_a[e * 8]);
    }
#pragma unroll
    for (int i = 0; i < TN / 32; ++i) {
      const int e = i * 256 + tid;
      const int r = e >> 3;
      const int cg = (e & 7) ^ (r & 7);
      async16(Bt + (size_t)(n0 + r) * K + kb + cg * 8, &lds_b[e * 8]);
    }
    __syncthreads();

#pragma unroll
    for (int ks = 0; ks < 64; ks += 32) {
      const int kc = (ks >> 3) + q;  // global k-chunk this lane needs
      bf16x8 av[4], bv[NI];
#pragma unroll
      for (int mi = 0; mi < 4; ++mi) {
        const int R = wm + mi * 16 + fr;
        av[mi] = *(const bf16x8*)&lds_a[R * 64 + ((kc ^ (R & 7)) << 3)];
      }
#pragma unroll
      for (int ni = 0; ni < NI; ++ni) {
        const int R = wn + ni * 16 + fr;
        bv[ni] = *(const bf16x8*)&lds_b[R * 64 + ((kc ^ (R & 7)) << 3)];
      }
#pragma unroll
      for (int mi = 0; mi < 4; ++mi)
#pragma unroll
        for (int ni = 0; ni < NI; ++ni)
          acc[mi][ni] = __builtin_amdgcn_mfma_f32_16x16x32_bf16(
              av[mi], bv[ni], acc[mi][ni], 0, 0, 0);
    }
    __syncthreads();
  }
}

// ---------------------------------------------------------------------------
// Merged projection GEMM, TN=128, grid (8, 64, 3): x = n-tile (fastest),
// y = m-tile, z selects {q,k,v}.
// z=0,1: bf16 row-major out [8192,1024]; z=2: vT[b][n][s] transposed out.
// ---------------------------------------------------------------------------
struct ProjArgs {
  const unsigned short* A[3];
  const unsigned short* Bt[3];
  unsigned short* C[3];
  const float* bias[3];
};

__global__ __launch_bounds__(256) void proj_gemm(ProjArgs p) {
  __shared__ __align__(16) unsigned short lds_a[128 * 64];
  __shared__ __align__(16) unsigned short lds_b[128 * 64];

  const int z = blockIdx.z;
  const int m0 = blockIdx.y * 128;
  const int n0 = blockIdx.x * 128;

  f32x4 acc[4][4] = {};
  gemm_loop<128>(p.A[z], p.Bt[z], lds_a, lds_b, 1024, m0, n0, acc);

  const int lane = threadIdx.x & 63;
  const int wave = threadIdx.x >> 6;
  const int wm = (wave >> 1) * 64;
  const int wn = (wave & 1) * 64;
  const int fr = lane & 15;
  const float* bias = p.bias[z];

  // C/D layout (m89/m91): col = lane&15 (+frag n), row = (lane>>4)*4 + reg.
  if (z != 2) {
    unsigned short* C = p.C[z];
#pragma unroll
    for (int mi = 0; mi < 4; ++mi) {
#pragma unroll
      for (int ni = 0; ni < 4; ++ni) {
        const int col = n0 + wn + ni * 16 + fr;
        const float bb = bias[col];
        const int rowb = m0 + wm + mi * 16 + (lane >> 4) * 4;
#pragma unroll
        for (int r = 0; r < 4; ++r)
          C[(size_t)(rowb + r) * 1024 + col] = f2b(acc[mi][ni][r] + bb);
      }
    }
  } else {
    // vT: per-batch [1024, 2048]; batch uniform per tile (m0 % 128 == 0).
    unsigned short* C = p.C[2] + (size_t)(m0 >> 11) * (2048 * 1024);
#pragma unroll
    for (int mi = 0; mi < 4; ++mi) {
#pragma unroll
      for (int ni = 0; ni < 4; ++ni) {
        const int col = n0 + wn + ni * 16 + fr;
        const float bb = bias[col];
        const int rowb = (m0 + wm + mi * 16 + (lane >> 4) * 4) & 2047;
        ushort4 o = make_ushort4(f2b(acc[mi][ni][0] + bb), f2b(acc[mi][ni][1] + bb),
                                 f2b(acc[mi][ni][2] + bb), f2b(acc[mi][ni][3] + bb));
        *(ushort4*)&C[(size_t)col * 2048 + rowb] = o;
      }
    }
  }
}

// ---------------------------------------------------------------------------
// Batched GEMM, fp32 out: C[bz][m,n] = sum_k A[bz][m,k] * Bt[bz][n,k]
// TN=128: 128x128 tile, 4 waves, 32 KiB LDS -> multiple blocks/CU.
// ---------------------------------------------------------------------------
template <int TN>
__global__ __launch_bounds__(256) void gemm_f32(
    const unsigned short* __restrict__ A, const unsigned short* __restrict__ Bt,
    float* __restrict__ C, int K, int ldc, long long sA, long long sB,
    long long sC) {
  __shared__ __align__(16) unsigned short lds_a[128 * 64];
  __shared__ __align__(16) unsigned short lds_b[TN * 64];
  const int bz = blockIdx.z;
  A += (long long)bz * sA;
  Bt += (long long)bz * sB;
  C += (long long)bz * sC;
  const int m0 = blockIdx.y * 128;
  const int n0 = blockIdx.x * TN;

  f32x4 acc[4][TN / 32] = {};
  gemm_loop<TN>(A, Bt, lds_a, lds_b, K, m0, n0, acc);

  const int lane = threadIdx.x & 63;
  const int wave = threadIdx.x >> 6;
  const int wm = (wave >> 1) * 64;
  const int wn = (wave & 1) * (TN / 2);
  const int fr = lane & 15;
#pragma unroll
  for (int mi = 0; mi < 4; ++mi) {
#pragma unroll
    for (int ni = 0; ni < TN / 32; ++ni) {
      const int col = n0 + wn + ni * 16 + fr;
      const int rowb = m0 + wm + mi * 16 + (lane >> 4) * 4;
#pragma unroll
      for (int r = 0; r < 4; ++r)
        C[(size_t)(rowb + r) * ldc + col] = acc[mi][ni][r];
    }
  }
}

// ---------------------------------------------------------------------------
// Merged cast fp32 -> bf16: blockIdx.y selects tensor {q,k,v}.
// ---------------------------------------------------------------------------
__global__ __launch_bounds__(256) void cast3(
    const float4* __restrict__ a, const float4* __restrict__ b,
    const float4* __restrict__ c, ushort4* __restrict__ oa,
    ushort4* __restrict__ ob, ushort4* __restrict__ oc, int n4) {
  const int i = blockIdx.x * 256 + threadIdx.x;
  if (i >= n4) return;
  const float4* src = (blockIdx.y == 0) ? a : (blockIdx.y == 1) ? b : c;
  ushort4* dst = (blockIdx.y == 0) ? oa : (blockIdx.y == 1) ? ob : oc;
  float4 v = src[i];
  dst[i] = make_ushort4(f2b(v.x), f2b(v.y), f2b(v.z), f2b(v.w));
}

// ---------------------------------------------------------------------------
// Merged cast + transpose W [K,N] fp32 -> WT [N,K] bf16; z selects weight.
// ---------------------------------------------------------------------------
__global__ __launch_bounds__(256) void transpose3(
    const float* __restrict__ w0, const float* __restrict__ w1,
    const float* __restrict__ w2, unsigned short* __restrict__ t0,
    unsigned short* __restrict__ t1, unsigned short* __restrict__ t2) {
  __shared__ float t[32][33];
  const int K = 1024, N = 1024;
  const float* W = (blockIdx.z == 0) ? w0 : (blockIdx.z == 1) ? w1 : w2;
  unsigned short* WT = (blockIdx.z == 0) ? t0 : (blockIdx.z == 1) ? t1 : t2;
  const int n0 = blockIdx.x * 32, k0 = blockIdx.y * 32;
  const int tx = threadIdx.x, ty = threadIdx.y;  // block (32,8)
#pragma unroll
  for (int i = 0; i < 32; i += 8)
    t[ty + i][tx] = W[(size_t)(k0 + ty + i) * N + (n0 + tx)];
  __syncthreads();
#pragma unroll
  for (int i = 0; i < 32; i += 8)
    WT[(size_t)(n0 + ty + i) * K + (k0 + tx)] = f2b(t[tx][ty + i]);
}

// ---------------------------------------------------------------------------
// Row softmax: P[row,:] = softmax(BETA * S[row,:]) as bf16. One block/row.
// ---------------------------------------------------------------------------
__global__ __launch_bounds__(256) void softmax_rows(const float* __restrict__ S,
                                                    unsigned short* __restrict__ P) {
  const int cols = 2048;
  const size_t row = blockIdx.x;
  const float4* srow = (const float4*)(S + row * cols);
  const int tid = threadIdx.x;
  const int lane = tid & 63;
  const int wave = tid >> 6;

  float4 a = srow[tid];
  float4 b = srow[tid + 256];

  float mx = fmaxf(fmaxf(fmaxf(a.x, a.y), fmaxf(a.z, a.w)),
                   fmaxf(fmaxf(b.x, b.y), fmaxf(b.z, b.w)));
#pragma unroll
  for (int o = 1; o < 64; o <<= 1) mx = fmaxf(mx, __shfl_xor(mx, o));

  __shared__ float red[8];
  if (lane == 0) red[wave] = mx;
  __syncthreads();
  mx = fmaxf(fmaxf(red[0], red[1]), fmaxf(red[2], red[3]));

  const float c = 0.03125f * 1.4426950408889634f;  // BETA * log2(e)
  float4 pa, pb;
  pa.x = exp2f((a.x - mx) * c); pa.y = exp2f((a.y - mx) * c);
  pa.z = exp2f((a.z - mx) * c); pa.w = exp2f((a.w - mx) * c);
  pb.x = exp2f((b.x - mx) * c); pb.y = exp2f((b.y - mx) * c);
  pb.z = exp2f((b.z - mx) * c); pb.w = exp2f((b.w - mx) * c);

  float sum = pa.x + pa.y + pa.z + pa.w + pb.x + pb.y + pb.z + pb.w;
#pragma unroll
  for (int o = 1; o < 64; o <<= 1) sum += __shfl_xor(sum, o);
  if (lane == 0) red[4 + wave] = sum;
  __syncthreads();
  sum = red[4] + red[5] + red[6] + red[7];

  const float inv = 1.0f / sum;
  ushort4* prow = (ushort4*)(P + row * cols);
  prow[tid] = make_ushort4(f2b(pa.x * inv), f2b(pa.y * inv), f2b(pa.z * inv),
                           f2b(pa.w * inv));
  prow[tid + 256] = make_ushort4(f2b(pb.x * inv), f2b(pb.y * inv),
                                 f2b(pb.z * inv), f2b(pb.w * inv));
}

// ---------------------------------------------------------------------------
extern "C" void kernel_launch(void* const* d_in, const int* in_sizes, int n_in,
                              void* d_out, int out_size, void* d_ws, size_t ws_size,
                              hipStream_t stream) {
  const float* query = (const float*)d_in[0];
  const float* key_ = (const float*)d_in[1];
  const float* value = (const float*)d_in[2];
  const float* Wq = (const float*)d_in[3];
  const float* bq = (const float*)d_in[4];
  const float* Wk = (const float*)d_in[5];
  const float* bk = (const float*)d_in[6];
  const float* Wv = (const float*)d_in[7];
  const float* bv = (const float*)d_in[8];
  float* out = (float*)d_out;

  char* ws = (char*)d_ws;
  // Workspace layout (peak 166 MiB):
  //   [0,6)      WqT/WkT/WvT bf16 [1024,1024]
  //   [6,54)     Xq/Xk/Xv bf16 [8192,1024]   (reused for P after projections)
  //   [54,102)   q bf16 [8192,1024], k bf16 [8192,1024], vT bf16 [4][1024,2048]
  //   [102,166)  scores fp32 [4,2048,2048]
  unsigned short* WqT = (unsigned short*)ws;
  unsigned short* WkT = WqT + (size_t)1024 * 1024;
  unsigned short* WvT = WkT + (size_t)1024 * 1024;
  unsigned short* Xq = (unsigned short*)(ws + 6 * MIB);
  unsigned short* Xk = Xq + (size_t)8192 * 1024;
  unsigned short* Xv = Xk + (size_t)8192 * 1024;
  unsigned short* qb = (unsigned short*)(ws + 54 * MIB);
  unsigned short* kb = (unsigned short*)(ws + 70 * MIB);
  unsigned short* vT = (unsigned short*)(ws + 86 * MIB);
  float* sc = (float*)(ws + 102 * MIB);
  unsigned short* P = (unsigned short*)(ws + 6 * MIB);  // reuse X region

  const int n4 = (4 * 2048 * 1024) / 4;
  cast3<<<dim3(n4 / 256, 3), 256, 0, stream>>>(
      (const float4*)query, (const float4*)key_, (const float4*)value,
      (ushort4*)Xq, (ushort4*)Xk, (ushort4*)Xv, n4);

  transpose3<<<dim3(32, 32, 3), dim3(32, 8), 0, stream>>>(Wq, Wk, Wv, WqT, WkT,
                                                          WvT);

  // All three projections: TN=128, grid (8,64,3) = 1536 blocks.
  ProjArgs pa;
  pa.A[0] = Xq;  pa.A[1] = Xk;  pa.A[2] = Xv;
  pa.Bt[0] = WqT; pa.Bt[1] = WkT; pa.Bt[2] = WvT;
  pa.C[0] = qb;  pa.C[1] = kb;  pa.C[2] = vT;
  pa.bias[0] = bq; pa.bias[1] = bk; pa.bias[2] = bv;
  proj_gemm<<<dim3(8, 64, 3), 256, 0, stream>>>(pa);

  // scores[b] = q[b] @ k[b]^T : M=N=2048, K=1024, fp32 out. 1024 blocks.
  gemm_f32<128><<<dim3(16, 16, 4), 256, 0, stream>>>(
      qb, kb, sc, 1024, 2048, 2048LL * 1024, 2048LL * 1024, 2048LL * 2048);

  // P = softmax(BETA * scores), bf16
  softmax_rows<<<8192, 256, 0, stream>>>(sc, P);

  // out[b] = P[b] @ v[b] : M=2048, N=1024, K=2048. 512 blocks, no split-K.
  gemm_f32<128><<<dim3(8, 16, 4), 256, 0, stream>>>(
      P, vT, out, 2048, 1024, 2048LL * 2048, 1024LL * 2048, 2048LL * 1024);
}

// Round 5
// 337.432 us; speedup vs baseline: 1.0255x; 1.0196x over previous
//
#include <hip/hip_runtime.h>

// ---------------------------------------------------------------------------
// Attention: out = softmax(BETA * (X_q Wq + bq)(X_k Wk + bk)^T) (X_v Wv + bv)
// B=4, S=2048, D=1024, KEY_DIM=VALUE_DIM=1024, BETA=1/32.
// R11 (from R10's m97-structure):
//  - 2-phase double-buffered K-loop: stage(t+1) issued BEFORE compute(t);
//    ONE __syncthreads per K-tile (its vmcnt(0)+lgkmcnt(0) is the wait).
//    Fragment reads are bare-asm ds_read_b128 (R9-proven) so the compiler
//    cannot insert a vmcnt drain between stage-issue and LDS reads;
//    lgkmcnt(0)+sched_barrier(0) guard the MFMA cluster (rule #18).
//  - Operand-swapped MFMA (D^T fragment) for q/k proj + fp32 GEMMs ->
//    lane owns 4 consecutive cols -> ushort4/float4 epilogue stores
//    (16 wide stores instead of 64 scalar). proj-v keeps unswapped (its
//    transposed vT output is already ushort4-contiguous).
//  - XOR-swizzled LDS kept (0 bank conflicts R6-R10).
// ---------------------------------------------------------------------------

typedef __bf16 bf16x8 __attribute__((ext_vector_type(8)));
typedef float f32x4 __attribute__((ext_vector_type(4)));

#define MIB ((size_t)1 << 20)

__device__ __forceinline__ unsigned short f2b(float f) {
  unsigned int u = __float_as_uint(f);
  return (unsigned short)((u + 0x7FFFu + ((u >> 16) & 1u)) >> 16);
}

__device__ __forceinline__ void async16(const void* g, void* l) {
  __builtin_amdgcn_global_load_lds(
      (const __attribute__((address_space(1))) unsigned int*)g,
      (__attribute__((address_space(3))) unsigned int*)l, 16, 0, 0);
}

// 32-bit LDS byte offset of a generic pointer known to point into LDS.
__device__ __forceinline__ unsigned ldsoff(const unsigned short* p) {
  return (unsigned)(size_t)(const __attribute__((address_space(3))) unsigned short*)p;
}

// Raw b128 LDS read, invisible to the compiler's waitcnt insertion.
__device__ __forceinline__ bf16x8 ds_read16(unsigned off) {
  bf16x8 r;
  asm volatile("ds_read_b128 %0, %1" : "=v"(r) : "v"(off));
  return r;
}

// ---------------------------------------------------------------------------
// Stage one K-tile (A:128x64 + B:TNx64 bf16) into LDS buffer `dst`.
// LDS slot (r,cc) holds global chunk (r, cc^(r&7)) (XOR swizzle, both-sides).
// ---------------------------------------------------------------------------
template <int TN>
__device__ __forceinline__ void stage_tile(
    const unsigned short* __restrict__ A, const unsigned short* __restrict__ Bt,
    unsigned short* dst, int K, int kb, int tid) {
#pragma unroll
  for (int i = 0; i < 4; ++i) {
    const int e = i * 256 + tid;  // chunk slot, 8 bf16 per chunk
    const int r = e >> 3;
    const int cg = (e & 7) ^ (r & 7);
    async16(A + (size_t)r * K + kb + cg * 8, dst + e * 8);
  }
#pragma unroll
  for (int i = 0; i < TN / 32; ++i) {
    const int e = i * 256 + tid;
    const int r = e >> 3;
    const int cg = (e & 7) ^ (r & 7);
    async16(Bt + (size_t)r * K + kb + cg * 8, dst + 128 * 64 + e * 8);
  }
}

// ---------------------------------------------------------------------------
// 2-phase double-buffered GEMM K-loop: acc += A[128xK] * Bt[TNxK]^T, BK=64.
// 4 waves 2x2; wave tile 64 x (TN/2). SWAP=true computes the transposed
// C-fragment (lane owns 4 consecutive n) for vectorized epilogues.
// lds must hold 2*(128+TN)*64 ushorts.
// ---------------------------------------------------------------------------
template <int TN, bool SWAP>
__device__ __forceinline__ void gemm_loop(
    const unsigned short* __restrict__ A, const unsigned short* __restrict__ Bt,
    unsigned short* lds, int K, int m0, int n0, f32x4 (&acc)[4][TN / 32]) {
  constexpr int NI = TN / 32;
  constexpr unsigned BUFB = (128 + TN) * 64 * 2;  // bytes per buffer
  const int tid = threadIdx.x;
  const int lane = tid & 63;
  const int wave = tid >> 6;
  const int wm = (wave >> 1) * 64;
  const int wn = (wave & 1) * (TN / 2);
  const int fr = lane & 15;
  const int q = lane >> 4;
  const int NT = K >> 6;

  const unsigned short* Ab = A + (size_t)m0 * K;
  const unsigned short* Bb = Bt + (size_t)n0 * K;
  const unsigned LB = ldsoff(lds);

  // Loop-invariant fragment byte offsets (within a buffer).
  unsigned oa[4][2], ob[NI][2];
#pragma unroll
  for (int mi = 0; mi < 4; ++mi) {
    const int R = wm + mi * 16 + fr;
#pragma unroll
    for (int ks = 0; ks < 2; ++ks) {
      const int kc = ks * 4 + q;
      oa[mi][ks] = (unsigned)((R * 64 + ((kc ^ (R & 7)) << 3)) * 2);
    }
  }
#pragma unroll
  for (int ni = 0; ni < NI; ++ni) {
    const int R = wn + ni * 16 + fr;
#pragma unroll
    for (int ks = 0; ks < 2; ++ks) {
      const int kc = ks * 4 + q;
      ob[ni][ks] =
          (unsigned)(128 * 64 * 2 + (R * 64 + ((kc ^ (R & 7)) << 3)) * 2);
    }
  }

  // Prologue: stage tile 0 into buffer 0.
  stage_tile<TN>(Ab, Bb, lds, K, 0, tid);
  __syncthreads();  // vmcnt(0) + barrier: tile 0 resident

  for (int t = 0; t < NT; ++t) {
    const unsigned boff = LB + (unsigned)(t & 1) * BUFB;
    // Issue next tile's stage first (hidden under this tile's compute).
    if (t + 1 < NT)
      stage_tile<TN>(Ab, Bb, lds + ((t + 1) & 1) * (BUFB / 2), K,
                     (t + 1) << 6, tid);

    bf16x8 av[2][4], bv[2][NI];
#pragma unroll
    for (int ks = 0; ks < 2; ++ks)
#pragma unroll
      for (int mi = 0; mi < 4; ++mi) av[ks][mi] = ds_read16(boff + oa[mi][ks]);
#pragma unroll
    for (int ks = 0; ks < 2; ++ks)
#pragma unroll
      for (int ni = 0; ni < NI; ++ni) bv[ks][ni] = ds_read16(boff + ob[ni][ks]);

    asm volatile("s_waitcnt lgkmcnt(0)");
    __builtin_amdgcn_sched_barrier(0);

#pragma unroll
    for (int ks = 0; ks < 2; ++ks)
#pragma unroll
      for (int mi = 0; mi < 4; ++mi)
#pragma unroll
        for (int ni = 0; ni < NI; ++ni)
          acc[mi][ni] = SWAP ? __builtin_amdgcn_mfma_f32_16x16x32_bf16(
                                   bv[ks][ni], av[ks][mi], acc[mi][ni], 0, 0, 0)
                             : __builtin_amdgcn_mfma_f32_16x16x32_bf16(
                                   av[ks][mi], bv[ks][ni], acc[mi][ni], 0, 0, 0);

    __syncthreads();  // vmcnt(0): tile t+1 resident; frees buffer t
  }
}

// ---------------------------------------------------------------------------
// q/k projection GEMM (SWAP layout), grid (8, 64, 2): z selects {q,k}.
// C bf16 row-major [8192,1024]; lane owns 4 consecutive cols -> ushort4.
// ---------------------------------------------------------------------------
struct ProjArgs {
  const unsigned short* A[3];
  const unsigned short* Bt[3];
  unsigned short* C[3];
  const float* bias[3];
};

__global__ __launch_bounds__(256) void proj_qk(ProjArgs p) {
  __shared__ __align__(16) unsigned short lds[2 * 256 * 64];
  const int z = blockIdx.z;
  const int m0 = blockIdx.y * 128;
  const int n0 = blockIdx.x * 128;

  f32x4 acc[4][4] = {};
  gemm_loop<128, true>(p.A[z], p.Bt[z], lds, 1024, m0, n0, acc);

  const int lane = threadIdx.x & 63;
  const int wave = threadIdx.x >> 6;
  const int wm = (wave >> 1) * 64;
  const int wn = (wave & 1) * 64;
  const int fr = lane & 15;
  const int q4 = (lane >> 4) * 4;
  const float* bias = p.bias[z];
  unsigned short* C = p.C[z];

  // SWAP layout: row m = fr (+16*mi), cols n = q4 + r (+16*ni), 4 consecutive.
#pragma unroll
  for (int mi = 0; mi < 4; ++mi) {
    const int m = m0 + wm + mi * 16 + fr;
#pragma unroll
    for (int ni = 0; ni < 4; ++ni) {
      const int nb = n0 + wn + ni * 16 + q4;
      const float4 bb = *(const float4*)&bias[nb];
      ushort4 o = make_ushort4(
          f2b(acc[mi][ni][0] + bb.x), f2b(acc[mi][ni][1] + bb.y),
          f2b(acc[mi][ni][2] + bb.z), f2b(acc[mi][ni][3] + bb.w));
      *(ushort4*)&C[(size_t)m * 1024 + nb] = o;
    }
  }
}

// ---------------------------------------------------------------------------
// v projection GEMM (unswapped), grid (8, 64, 1): writes vT[b][n][s].
// ---------------------------------------------------------------------------
__global__ __launch_bounds__(256) void proj_v(ProjArgs p) {
  __shared__ __align__(16) unsigned short lds[2 * 256 * 64];
  const int m0 = blockIdx.y * 128;
  const int n0 = blockIdx.x * 128;

  f32x4 acc[4][4] = {};
  gemm_loop<128, false>(p.A[2], p.Bt[2], lds, 1024, m0, n0, acc);

  const int lane = threadIdx.x & 63;
  const int wave = threadIdx.x >> 6;
  const int wm = (wave >> 1) * 64;
  const int wn = (wave & 1) * 64;
  const int fr = lane & 15;
  const int q4 = (lane >> 4) * 4;
  const float* bias = p.bias[2];

  // vT: per-batch [1024, 2048]; batch uniform per tile. Unswapped layout:
  // col n = fr (+16*ni), rows m = q4 + r (+16*mi) -> ushort4 along m.
  unsigned short* C = p.C[2] + (size_t)(m0 >> 11) * (2048 * 1024);
#pragma unroll
  for (int mi = 0; mi < 4; ++mi) {
#pragma unroll
    for (int ni = 0; ni < 4; ++ni) {
      const int col = n0 + wn + ni * 16 + fr;
      const float bb = bias[col];
      const int rowb = (m0 + wm + mi * 16 + q4) & 2047;
      ushort4 o =
          make_ushort4(f2b(acc[mi][ni][0] + bb), f2b(acc[mi][ni][1] + bb),
                       f2b(acc[mi][ni][2] + bb), f2b(acc[mi][ni][3] + bb));
      *(ushort4*)&C[(size_t)col * 2048 + rowb] = o;
    }
  }
}

// ---------------------------------------------------------------------------
// Batched GEMM, fp32 out (SWAP layout -> float4 stores):
// C[bz][m,n] = sum_k A[bz][m,k] * Bt[bz][n,k]
// ---------------------------------------------------------------------------
__global__ __launch_bounds__(256) void gemm_f32(
    const unsigned short* __restrict__ A, const unsigned short* __restrict__ Bt,
    float* __restrict__ C, int K, int ldc, long long sA, long long sB,
    long long sC) {
  __shared__ __align__(16) unsigned short lds[2 * 256 * 64];
  const int bz = blockIdx.z;
  A += (long long)bz * sA;
  Bt += (long long)bz * sB;
  C += (long long)bz * sC;
  const int m0 = blockIdx.y * 128;
  const int n0 = blockIdx.x * 128;

  f32x4 acc[4][4] = {};
  gemm_loop<128, true>(A, Bt, lds, K, m0, n0, acc);

  const int lane = threadIdx.x & 63;
  const int wave = threadIdx.x >> 6;
  const int wm = (wave >> 1) * 64;
  const int wn = (wave & 1) * 64;
  const int fr = lane & 15;
  const int q4 = (lane >> 4) * 4;
#pragma unroll
  for (int mi = 0; mi < 4; ++mi) {
    const int m = m0 + wm + mi * 16 + fr;
#pragma unroll
    for (int ni = 0; ni < 4; ++ni) {
      const int nb = n0 + wn + ni * 16 + q4;
      *(f32x4*)&C[(size_t)m * ldc + nb] = acc[mi][ni];
    }
  }
}

// ---------------------------------------------------------------------------
// Merged cast fp32 -> bf16: blockIdx.y selects tensor {q,k,v}.
// ---------------------------------------------------------------------------
__global__ __launch_bounds__(256) void cast3(
    const float4* __restrict__ a, const float4* __restrict__ b,
    const float4* __restrict__ c, ushort4* __restrict__ oa,
    ushort4* __restrict__ ob, ushort4* __restrict__ oc, int n4) {
  const int i = blockIdx.x * 256 + threadIdx.x;
  if (i >= n4) return;
  const float4* src = (blockIdx.y == 0) ? a : (blockIdx.y == 1) ? b : c;
  ushort4* dst = (blockIdx.y == 0) ? oa : (blockIdx.y == 1) ? ob : oc;
  float4 v = src[i];
  dst[i] = make_ushort4(f2b(v.x), f2b(v.y), f2b(v.z), f2b(v.w));
}

// ---------------------------------------------------------------------------
// Merged cast + transpose W [K,N] fp32 -> WT [N,K] bf16; z selects weight.
// ---------------------------------------------------------------------------
__global__ __launch_bounds__(256) void transpose3(
    const float* __restrict__ w0, const float* __restrict__ w1,
    const float* __restrict__ w2, unsigned short* __restrict__ t0,
    unsigned short* __restrict__ t1, unsigned short* __restrict__ t2) {
  __shared__ float t[32][33];
  const int K = 1024, N = 1024;
  const float* W = (blockIdx.z == 0) ? w0 : (blockIdx.z == 1) ? w1 : w2;
  unsigned short* WT = (blockIdx.z == 0) ? t0 : (blockIdx.z == 1) ? t1 : t2;
  const int n0 = blockIdx.x * 32, k0 = blockIdx.y * 32;
  const int tx = threadIdx.x, ty = threadIdx.y;  // block (32,8)
#pragma unroll
  for (int i = 0; i < 32; i += 8)
    t[ty + i][tx] = W[(size_t)(k0 + ty + i) * N + (n0 + tx)];
  __syncthreads();
#pragma unroll
  for (int i = 0; i < 32; i += 8)
    WT[(size_t)(n0 + ty + i) * K + (k0 + tx)] = f2b(t[tx][ty + i]);
}

// ---------------------------------------------------------------------------
// Row softmax: P[row,:] = softmax(BETA * S[row,:]) as bf16. One block/row.
// ---------------------------------------------------------------------------
__global__ __launch_bounds__(256) void softmax_rows(const float* __restrict__ S,
                                                    unsigned short* __restrict__ P) {
  const int cols = 2048;
  const size_t row = blockIdx.x;
  const float4* srow = (const float4*)(S + row * cols);
  const int tid = threadIdx.x;
  const int lane = tid & 63;
  const int wave = tid >> 6;

  float4 a = srow[tid];
  float4 b = srow[tid + 256];

  float mx = fmaxf(fmaxf(fmaxf(a.x, a.y), fmaxf(a.z, a.w)),
                   fmaxf(fmaxf(b.x, b.y), fmaxf(b.z, b.w)));
#pragma unroll
  for (int o = 1; o < 64; o <<= 1) mx = fmaxf(mx, __shfl_xor(mx, o));

  __shared__ float red[8];
  if (lane == 0) red[wave] = mx;
  __syncthreads();
  mx = fmaxf(fmaxf(red[0], red[1]), fmaxf(red[2], red[3]));

  const float c = 0.03125f * 1.4426950408889634f;  // BETA * log2(e)
  float4 pa, pb;
  pa.x = exp2f((a.x - mx) * c); pa.y = exp2f((a.y - mx) * c);
  pa.z = exp2f((a.z - mx) * c); pa.w = exp2f((a.w - mx) * c);
  pb.x = exp2f((b.x - mx) * c); pb.y = exp2f((b.y - mx) * c);
  pb.z = exp2f((b.z - mx) * c); pb.w = exp2f((b.w - mx) * c);

  float sum = pa.x + pa.y + pa.z + pa.w + pb.x + pb.y + pb.z + pb.w;
#pragma unroll
  for (int o = 1; o < 64; o <<= 1) sum += __shfl_xor(sum, o);
  if (lane == 0) red[4 + wave] = sum;
  __syncthreads();
  sum = red[4] + red[5] + red[6] + red[7];

  const float inv = 1.0f / sum;
  ushort4* prow = (ushort4*)(P + row * cols);
  prow[tid] = make_ushort4(f2b(pa.x * inv), f2b(pa.y * inv), f2b(pa.z * inv),
                           f2b(pa.w * inv));
  prow[tid + 256] = make_ushort4(f2b(pb.x * inv), f2b(pb.y * inv),
                                 f2b(pb.z * inv), f2b(pb.w * inv));
}

// ---------------------------------------------------------------------------
extern "C" void kernel_launch(void* const* d_in, const int* in_sizes, int n_in,
                              void* d_out, int out_size, void* d_ws, size_t ws_size,
                              hipStream_t stream) {
  const float* query = (const float*)d_in[0];
  const float* key_ = (const float*)d_in[1];
  const float* value = (const float*)d_in[2];
  const float* Wq = (const float*)d_in[3];
  const float* bq = (const float*)d_in[4];
  const float* Wk = (const float*)d_in[5];
  const float* bk = (const float*)d_in[6];
  const float* Wv = (const float*)d_in[7];
  const float* bv = (const float*)d_in[8];
  float* out = (float*)d_out;

  char* ws = (char*)d_ws;
  // Workspace layout (peak 166 MiB):
  //   [0,6)      WqT/WkT/WvT bf16 [1024,1024]
  //   [6,54)     Xq/Xk/Xv bf16 [8192,1024]   (reused for P after projections)
  //   [54,102)   q bf16 [8192,1024], k bf16 [8192,1024], vT bf16 [4][1024,2048]
  //   [102,166)  scores fp32 [4,2048,2048]
  unsigned short* WqT = (unsigned short*)ws;
  unsigned short* WkT = WqT + (size_t)1024 * 1024;
  unsigned short* WvT = WkT + (size_t)1024 * 1024;
  unsigned short* Xq = (unsigned short*)(ws + 6 * MIB);
  unsigned short* Xk = Xq + (size_t)8192 * 1024;
  unsigned short* Xv = Xk + (size_t)8192 * 1024;
  unsigned short* qb = (unsigned short*)(ws + 54 * MIB);
  unsigned short* kb = (unsigned short*)(ws + 70 * MIB);
  unsigned short* vT = (unsigned short*)(ws + 86 * MIB);
  float* sc = (float*)(ws + 102 * MIB);
  unsigned short* P = (unsigned short*)(ws + 6 * MIB);  // reuse X region

  const int n4 = (4 * 2048 * 1024) / 4;
  cast3<<<dim3(n4 / 256, 3), 256, 0, stream>>>(
      (const float4*)query, (const float4*)key_, (const float4*)value,
      (ushort4*)Xq, (ushort4*)Xk, (ushort4*)Xv, n4);

  transpose3<<<dim3(32, 32, 3), dim3(32, 8), 0, stream>>>(Wq, Wk, Wv, WqT, WkT,
                                                          WvT);

  ProjArgs pa;
  pa.A[0] = Xq;  pa.A[1] = Xk;  pa.A[2] = Xv;
  pa.Bt[0] = WqT; pa.Bt[1] = WkT; pa.Bt[2] = WvT;
  pa.C[0] = qb;  pa.C[1] = kb;  pa.C[2] = vT;
  pa.bias[0] = bq; pa.bias[1] = bk; pa.bias[2] = bv;

  // q,k projections: swapped layout, ushort4 stores. 1024 blocks.
  proj_qk<<<dim3(8, 64, 2), 256, 0, stream>>>(pa);
  // v projection: unswapped, transposed vT out. 512 blocks.
  proj_v<<<dim3(8, 64, 1), 256, 0, stream>>>(pa);

  // scores[b] = q[b] @ k[b]^T : M=N=2048, K=1024, fp32 out. 1024 blocks.
  gemm_f32<<<dim3(16, 16, 4), 256, 0, stream>>>(
      qb, kb, sc, 1024, 2048, 2048LL * 1024, 2048LL * 1024, 2048LL * 2048);

  // P = softmax(BETA * scores), bf16
  softmax_rows<<<8192, 256, 0, stream>>>(sc, P);

  // out[b] = P[b] @ v[b] : M=2048, N=1024, K=2048. 512 blocks.
  gemm_f32<<<dim3(8, 16, 4), 256, 0, stream>>>(
      P, vT, out, 2048, 1024, 2048LL * 2048, 1024LL * 2048, 2048LL * 1024);
}